// Round 10
// baseline (6475.011 us; speedup 1.0000x reference)
//
#include <hip/hip_runtime.h>

// ---------------------------------------------------------------------------
// Child-Sum TreeLSTM, complete binary tree, level-wise bottom-up, bf16 MFMA.
// Round 10: barrier-free, LDS-free, wave-independent design.
//   Every no-spill variant (R2/R4/R7) plateaued at ~380-400us with nothing
//   saturated -> latency/MLP-bound, caused by barrier phase-locking + short
//   dependent chains. Spilling variants hit 2.3-4.5 TB/s -> memory system
//   has headroom. Fix: one wave = one 32-node tile, A-frags loaded directly
//   from global in MFMA fragment order, no LDS, no __syncthreads; waves
//   free-run and cover each other's latency. Pass split keeps <=2 acc planes
//   live (peak ~110 VGPR). launch_bounds(256,4) -> 128-reg cap under both
//   plausible semantics of arg2.
//
// mfma_f32_32x32x16_bf16: A lane: row=l&31, k=(l>>5)*8+e  (16B/lane)
//                         B lane: col=l&31, k=(l>>5)*8+e = W[col][k] (16B)
//                         D: col=l&31, row=(r&3)+8*(r>>2)+4*(l>>5), r=0..15
// ---------------------------------------------------------------------------

typedef __attribute__((ext_vector_type(8))) short bf16x8;
typedef __attribute__((ext_vector_type(8))) unsigned short us8;
typedef __attribute__((ext_vector_type(16))) float f32x16;
typedef __attribute__((ext_vector_type(4))) float f4;

#define MFMA32(A, B, C) __builtin_amdgcn_mfma_f32_32x32x16_bf16(A, B, C, 0, 0, 0)

__device__ __forceinline__ unsigned short f2b(float f) {
  unsigned int u = __builtin_bit_cast(unsigned int, f);
  u = u + 0x7FFFu + ((u >> 16) & 1u);   // RNE
  return (unsigned short)(u >> 16);
}
__device__ __forceinline__ float bf2f(unsigned short u) {
  unsigned int v = (unsigned int)u << 16;
  return __builtin_bit_cast(float, v);
}
__device__ __forceinline__ us8 pack8(f4 a, f4 b) {
  us8 r;
  r[0] = f2b(a[0]); r[1] = f2b(a[1]); r[2] = f2b(a[2]); r[3] = f2b(a[3]);
  r[4] = f2b(b[0]); r[5] = f2b(b[1]); r[6] = f2b(b[2]); r[7] = f2b(b[3]);
  return r;
}
__device__ __forceinline__ float sigm(float x) { return 1.0f / (1.0f + __expf(-x)); }
__device__ __forceinline__ float tanh_f(float x) { return 2.0f / (1.0f + __expf(-2.0f * x)) - 1.0f; }
__device__ __forceinline__ f32x16 zz16() {
  f32x16 v;
  #pragma unroll
  for (int i = 0; i < 16; ++i) v[i] = 0.f;
  return v;
}

__global__ void pack_w(const float* __restrict__ a,  // Wioux 768x256
                       const float* __restrict__ b,  // Wiouh 768x256
                       const float* __restrict__ c,  // Wfx   256x256
                       const float* __restrict__ d,  // Wfh   256x256
                       unsigned short* __restrict__ out) {
  int i = blockIdx.x * blockDim.x + threadIdx.x;  // 0 .. 524287
  const int A = 768 * 256;
  const int B = A + 768 * 256;
  const int C = B + 256 * 256;
  float v;
  if (i < A)      v = a[i];
  else if (i < B) v = b[i - A];
  else if (i < C) v = c[i - B];
  else            v = d[i - C];
  out[i] = f2b(v);
}

// convert ALL node x rows to bf16 (8 elems/thread)
__global__ void conv_x(const float* __restrict__ x, unsigned short* __restrict__ xb, int n8) {
  int i = blockIdx.x * blockDim.x + threadIdx.x;
  if (i >= n8) return;
  f4 a = __builtin_nontemporal_load((const f4*)(x + (size_t)i * 8));
  f4 b = __builtin_nontemporal_load((const f4*)(x + (size_t)i * 8 + 4));
  __builtin_nontemporal_store(pack8(a, b), (us8*)(xb + (size_t)i * 8));
}

template<int LEAF>
__global__ __launch_bounds__(256, 4) void level_k(
    const unsigned short* __restrict__ xb,     // [N][256] bf16, global node idx
    const unsigned short* __restrict__ Wx,     // bf16 Wioux [768][256]
    const unsigned short* __restrict__ Wh,     // bf16 Wiouh [768][256]
    const unsigned short* __restrict__ Wfxw,   // bf16 Wfx   [256][256]
    const unsigned short* __restrict__ Wfhw,   // bf16 Wfh   [256][256]
    const float* __restrict__ bioux,
    const float* __restrict__ bfx,
    const float* __restrict__ fb,
    float* __restrict__ h_all,                 // d_out + 512, global node idx
    unsigned short* __restrict__ cb_cur,       // level-local [L][256] bf16
    const unsigned short* __restrict__ cb_next,
    unsigned short* __restrict__ hb_cur,
    const unsigned short* __restrict__ hb_next,
    float* __restrict__ out0,                  // d_out (h_root | c_root)
    int s, int L, int T, int root)
{
  const int tid  = threadIdx.x;
  const int lane = tid & 63;
  const int wv   = tid >> 6;          // 0..3
  const int lr   = lane & 31;         // A node-row / B output-col within tile
  const int kh   = lane >> 5;         // k half
  const int NW   = gridDim.x * 4;

  for (int t = blockIdx.x * 4 + wv; t < T; t += NW) {
    const int nb0 = t * 32;
    // per-lane A-frag row bases (k-offset folds to base + kh*16B; kt*32B is imm)
    const unsigned short* xrow  = xb + (size_t)(s + nb0 + lr) * 256 + kh * 8;
    const unsigned short* h1row = LEAF ? xrow
        : hb_next + (size_t)(2 * (nb0 + lr)) * 256 + kh * 8;   // h2 = h1row + 256

    for (int cg = 0; cg < 8; ++cg) {
      const int colc = cg * 32 + lr;
      const unsigned short* bi_p = Wx + (size_t)colc * 256 + kh * 8;
      const unsigned short* bo_p = bi_p + 65536;
      const unsigned short* bu_p = bi_p + 131072;
      const float bi_ = bioux[colc];
      const float bo_ = bioux[256 + colc];
      const float bu_ = bioux[512 + colc];

      if (!LEAF) {
        const float bf_ = bfx[colc] + fb[colc];
        const unsigned short* bfx_p = Wfxw + (size_t)colc * 256 + kh * 8;
        const unsigned short* bfh_p = Wfhw + (size_t)colc * 256 + kh * 8;
        const unsigned short* bih_p = Wh + (size_t)colc * 256 + kh * 8;
        const unsigned short* boh_p = bih_p + 65536;
        const unsigned short* buh_p = bih_p + 131072;

        // ---- P1: xf = x @ Wfx^T (1 plane) ----
        f32x16 axf = zz16();
        #pragma unroll 4
        for (int kt = 0; kt < 16; ++kt) {
          bf16x8 a = *(const bf16x8*)(xrow + kt * 16);
          bf16x8 b = *(const bf16x8*)(bfx_p + kt * 16);
          axf = MFMA32(a, b, axf);
        }
        float xf[16];
        #pragma unroll
        for (int r = 0; r < 16; ++r) xf[r] = axf[r] + bf_;

        // ---- children c gathers (64B/half-wave segments) ----
        float c1v[16], c2v[16];
        #pragma unroll
        for (int r = 0; r < 16; ++r) {
          const int m = (r & 3) + 8 * (r >> 2) + 4 * kh;
          const size_t cbo = (size_t)(2 * (nb0 + m)) * 256 + colc;
          c1v[r] = bf2f(cb_next[cbo]);
          c2v[r] = bf2f(cb_next[cbo + 256]);
        }

        // ---- P2: f1 = h1@Wfh^T, f2 = h2@Wfh^T (2 planes, shared B) ----
        f32x16 f1 = zz16(), f2 = zz16();
        #pragma unroll 2
        for (int kt = 0; kt < 16; ++kt) {
          bf16x8 a1 = *(const bf16x8*)(h1row + kt * 16);
          bf16x8 a2 = *(const bf16x8*)(h1row + 256 + kt * 16);
          bf16x8 bf = *(const bf16x8*)(bfh_p + kt * 16);
          f1 = MFMA32(a1, bf, f1);
          f2 = MFMA32(a2, bf, f2);
        }
        float cv[16];
        #pragma unroll
        for (int r = 0; r < 16; ++r)
          cv[r] = sigm(xf[r] + f1[r]) * c1v[r] + sigm(xf[r] + f2[r]) * c2v[r];

        // ---- P3: i,u (2 planes; A shared x,h1,h2) ----
        f32x16 ai = zz16(), au = zz16();
        #pragma unroll 1
        for (int kt = 0; kt < 16; ++kt) {
          bf16x8 ax = *(const bf16x8*)(xrow + kt * 16);
          bf16x8 a1 = *(const bf16x8*)(h1row + kt * 16);
          bf16x8 a2 = *(const bf16x8*)(h1row + 256 + kt * 16);
          bf16x8 bix = *(const bf16x8*)(bi_p + kt * 16);
          bf16x8 bux = *(const bf16x8*)(bu_p + kt * 16);
          bf16x8 bih = *(const bf16x8*)(bih_p + kt * 16);
          bf16x8 buh = *(const bf16x8*)(buh_p + kt * 16);
          ai = MFMA32(ax, bix, ai);
          ai = MFMA32(a1, bih, ai);
          ai = MFMA32(a2, bih, ai);
          au = MFMA32(ax, bux, au);
          au = MFMA32(a1, buh, au);
          au = MFMA32(a2, buh, au);
        }
        #pragma unroll
        for (int r = 0; r < 16; ++r)
          cv[r] += sigm(ai[r] + bi_) * tanh_f(au[r] + bu_);

        // ---- P4: o (1 plane) ----
        f32x16 ao = zz16();
        #pragma unroll 2
        for (int kt = 0; kt < 16; ++kt) {
          bf16x8 ax = *(const bf16x8*)(xrow + kt * 16);
          bf16x8 a1 = *(const bf16x8*)(h1row + kt * 16);
          bf16x8 a2 = *(const bf16x8*)(h1row + 256 + kt * 16);
          bf16x8 box = *(const bf16x8*)(bo_p + kt * 16);
          bf16x8 boh = *(const bf16x8*)(boh_p + kt * 16);
          ao = MFMA32(ax, box, ao);
          ao = MFMA32(a1, boh, ao);
          ao = MFMA32(a2, boh, ao);
        }

        // ---- epilogue ----
        #pragma unroll
        for (int r = 0; r < 16; ++r) {
          const int m = (r & 3) + 8 * (r >> 2) + 4 * kh;
          const int j = nb0 + m;
          if (j >= L) continue;
          const size_t n = (size_t)(s + j);
          const float c_ = cv[r];
          const float hv = sigm(ao[r] + bo_) * tanh_f(c_);
          __builtin_nontemporal_store(hv, h_all + n * 256 + colc);
          cb_cur[(size_t)j * 256 + colc] = f2b(c_);
          hb_cur[(size_t)j * 256 + colc] = f2b(hv);
          if (root && j == 0) { out0[colc] = hv; out0[256 + colc] = c_; }
        }
      } else {
        // ---- leaf: i,u then o, x only ----
        f32x16 ai = zz16(), au = zz16();
        #pragma unroll 2
        for (int kt = 0; kt < 16; ++kt) {
          bf16x8 ax  = *(const bf16x8*)(xrow + kt * 16);
          bf16x8 bix = *(const bf16x8*)(bi_p + kt * 16);
          bf16x8 bux = *(const bf16x8*)(bu_p + kt * 16);
          ai = MFMA32(ax, bix, ai);
          au = MFMA32(ax, bux, au);
        }
        float cv[16];
        #pragma unroll
        for (int r = 0; r < 16; ++r)
          cv[r] = sigm(ai[r] + bi_) * tanh_f(au[r] + bu_);

        f32x16 ao = zz16();
        #pragma unroll 4
        for (int kt = 0; kt < 16; ++kt) {
          bf16x8 ax  = *(const bf16x8*)(xrow + kt * 16);
          bf16x8 box = *(const bf16x8*)(bo_p + kt * 16);
          ao = MFMA32(ax, box, ao);
        }

        #pragma unroll
        for (int r = 0; r < 16; ++r) {
          const int m = (r & 3) + 8 * (r >> 2) + 4 * kh;
          const int j = nb0 + m;
          if (j >= L) continue;
          const size_t n = (size_t)(s + j);
          const float c_ = cv[r];
          const float hv = sigm(ao[r] + bo_) * tanh_f(c_);
          __builtin_nontemporal_store(hv, h_all + n * 256 + colc);
          cb_cur[(size_t)j * 256 + colc] = f2b(c_);
          hb_cur[(size_t)j * 256 + colc] = f2b(hv);
        }
      }
    }
  }
}

extern "C" void kernel_launch(void* const* d_in, const int* in_sizes, int n_in,
                              void* d_out, int out_size, void* d_ws, size_t ws_size,
                              hipStream_t stream) {
  const float* inputs = (const float*)d_in[0];
  const float* Wioux  = (const float*)d_in[1];
  const float* bioux  = (const float*)d_in[2];
  const float* Wiouh  = (const float*)d_in[3];
  const float* Wfx    = (const float*)d_in[4];
  const float* bfx    = (const float*)d_in[5];
  const float* Wfh    = (const float*)d_in[6];
  const float* fb     = (const float*)d_in[7];

  const int N = in_sizes[0] / 256;       // 262143
  int depth = 0;
  while (((1 << depth) - 1) < N) ++depth;  // 18
  const int LF = (N + 1) / 2;            // 131072 leaves

  float* out   = (float*)d_out;
  float* h_all = out + 512;

  // ws carve (bytes): cb ping-pong bf16, hb ping-pong bf16, xb (all nodes) bf16, weights
  char* p = (char*)d_ws;
  unsigned short* cb_even = (unsigned short*)p; p += (size_t)(LF / 2) * 256 * 2;
  unsigned short* cb_odd  = (unsigned short*)p; p += (size_t)LF * 256 * 2;
  unsigned short* hb_even = (unsigned short*)p; p += (size_t)(LF / 2) * 256 * 2;
  unsigned short* hb_odd  = (unsigned short*)p; p += (size_t)LF * 256 * 2;
  unsigned short* xb      = (unsigned short*)p; p += (size_t)N * 256 * 2;
  unsigned short* wb      = (unsigned short*)p;

  pack_w<<<2048, 256, 0, stream>>>(Wioux, Wiouh, Wfx, Wfh, wb);
  {
    const int n8 = (N * 256) / 8;   // all-node elems / 8
    conv_x<<<(n8 + 255) / 256, 256, 0, stream>>>(inputs, xb, n8);
  }

  const unsigned short* pWx  = wb;
  const unsigned short* pWh  = wb + 768 * 256;
  const unsigned short* pWfx = wb + 2 * 768 * 256;
  const unsigned short* pWfh = wb + 2 * 768 * 256 + 256 * 256;

  for (int d = depth - 1; d >= 0; --d) {
    const int L = 1 << d;
    const int s = L - 1;
    const int T = (L + 31) / 32;
    const int G = T < 1024 ? T : 1024;
    unsigned short* cb_cur = (d & 1) ? cb_odd : cb_even;
    const unsigned short* cb_next = ((d + 1) & 1) ? cb_odd : cb_even;
    unsigned short* hb_cur = (d & 1) ? hb_odd : hb_even;
    const unsigned short* hb_next = ((d + 1) & 1) ? hb_odd : hb_even;
    if (d == depth - 1) {
      level_k<1><<<G, 256, 0, stream>>>(
          xb, pWx, pWh, pWfx, pWfh, bioux, bfx, fb,
          h_all, cb_cur, cb_next, hb_cur, hb_next, out, s, L, T, 0);
    } else {
      level_k<0><<<G, 256, 0, stream>>>(
          xb, pWx, pWh, pWfx, pWfh, bioux, bfx, fb,
          h_all, cb_cur, cb_next, hb_cur, hb_next, out, s, L, T, (d == 0) ? 1 : 0);
    }
  }
}

// Round 11
// 1260.280 us; speedup vs baseline: 5.1378x; 5.1378x over previous
//
#include <hip/hip_runtime.h>

// ---------------------------------------------------------------------------
// Child-Sum TreeLSTM, complete binary tree, level-wise bottom-up, bf16 MFMA.
// Round 11: WEIGHTS RESIDENT IN LDS. R2/R4/R7 all ceiling'd at ~400us/level
// re-streaming 2.4 GB of weights from L3 (stream evicts them from L2). Now:
// 256 output cols split into 8 groups of 32; per group all 8 weight planes
// (32 cols x 256 k x {Wx_i,Wx_o,Wx_u,Wh_i,Wh_o,Wh_u,Wfx,Wfh}) = 131 KB LDS,
// staged ONCE per block. Grid = 8 cg x 32 stripes = 256 blocks (1/CU);
// bid = cg*32+stripe => the 8 cg-blocks of a stripe share an XCD (bid%8) so
// node data is HBM-fetched once and L2-served 8x. 8 waves free-run (no
// barriers after staging); A-frags from global in fragment order; B-frags
// from LDS conflict-free (fragment-major layout). Pass split keeps ~95 VGPR.
//
// mfma_f32_32x32x16_bf16: A lane: row=l&31, k=(l>>5)*8+e  (16B/lane)
//                         B lane: col=l&31, k=(l>>5)*8+e = W[col][k] (16B)
//                         D: col=l&31, row=(r&3)+8*(r>>2)+4*(l>>5), r=0..15
// ---------------------------------------------------------------------------

typedef __attribute__((ext_vector_type(8))) short bf16x8;
typedef __attribute__((ext_vector_type(8))) unsigned short us8;
typedef __attribute__((ext_vector_type(16))) float f32x16;
typedef __attribute__((ext_vector_type(4))) float f4;

#define MFMA32(A, B, C) __builtin_amdgcn_mfma_f32_32x32x16_bf16(A, B, C, 0, 0, 0)

__device__ __forceinline__ unsigned short f2b(float f) {
  unsigned int u = __builtin_bit_cast(unsigned int, f);
  u = u + 0x7FFFu + ((u >> 16) & 1u);   // RNE
  return (unsigned short)(u >> 16);
}
__device__ __forceinline__ float bf2f(unsigned short u) {
  unsigned int v = (unsigned int)u << 16;
  return __builtin_bit_cast(float, v);
}
__device__ __forceinline__ us8 pack8(f4 a, f4 b) {
  us8 r;
  r[0] = f2b(a[0]); r[1] = f2b(a[1]); r[2] = f2b(a[2]); r[3] = f2b(a[3]);
  r[4] = f2b(b[0]); r[5] = f2b(b[1]); r[6] = f2b(b[2]); r[7] = f2b(b[3]);
  return r;
}
__device__ __forceinline__ float sigm(float x) { return 1.0f / (1.0f + __expf(-x)); }
__device__ __forceinline__ float tanh_f(float x) { return 2.0f / (1.0f + __expf(-2.0f * x)) - 1.0f; }
__device__ __forceinline__ f32x16 zz16() {
  f32x16 v;
  #pragma unroll
  for (int i = 0; i < 16; ++i) v[i] = 0.f;
  return v;
}

__global__ void pack_w(const float* __restrict__ a,  // Wioux 768x256
                       const float* __restrict__ b,  // Wiouh 768x256
                       const float* __restrict__ c,  // Wfx   256x256
                       const float* __restrict__ d,  // Wfh   256x256
                       unsigned short* __restrict__ out) {
  int i = blockIdx.x * blockDim.x + threadIdx.x;  // 0 .. 524287
  const int A = 768 * 256;
  const int B = A + 768 * 256;
  const int C = B + 256 * 256;
  float v;
  if (i < A)      v = a[i];
  else if (i < B) v = b[i - A];
  else if (i < C) v = c[i - B];
  else            v = d[i - C];
  out[i] = f2b(v);
}

// convert ALL node x rows to bf16 (8 elems/thread)
__global__ void conv_x(const float* __restrict__ x, unsigned short* __restrict__ xb, int n8) {
  int i = blockIdx.x * blockDim.x + threadIdx.x;
  if (i >= n8) return;
  f4 a = __builtin_nontemporal_load((const f4*)(x + (size_t)i * 8));
  f4 b = __builtin_nontemporal_load((const f4*)(x + (size_t)i * 8 + 4));
  __builtin_nontemporal_store(pack8(a, b), (us8*)(xb + (size_t)i * 8));
}

template<int LEAF>
__global__ __launch_bounds__(512, 2) void level_k(
    const unsigned short* __restrict__ xb,     // [N][256] bf16, global node idx
    const unsigned short* __restrict__ wb,     // packed bf16 weights (524288)
    const float* __restrict__ bioux,
    const float* __restrict__ bfx,
    const float* __restrict__ fb,
    float* __restrict__ h_all,                 // d_out + 512, global node idx
    unsigned short* __restrict__ cb_cur,       // level-local [L][256] bf16
    const unsigned short* __restrict__ cb_next,
    unsigned short* __restrict__ hb_cur,
    const unsigned short* __restrict__ hb_next,
    float* __restrict__ out0,                  // d_out (h_root | c_root)
    int s, int L, int T, int root)
{
  extern __shared__ unsigned short W[];  // [NP][16kt][2kh][32col][8e]

  const int tid    = threadIdx.x;
  const int cg     = blockIdx.x >> 5;    // 0..7 column group
  const int stripe = blockIdx.x & 31;    // 0..31 node stripe (XCD = stripe%8)

  // ---- stage this column-group's weight planes into LDS (once) ----
  const int NP = LEAF ? 3 : 8;
  for (int c = tid; c < NP * 1024; c += 512) {
    const int p   = c >> 10;
    const int r10 = c & 1023;
    const int kt  = r10 >> 6;
    const int khs = (r10 >> 5) & 1;
    const int col = r10 & 31;
    // plane source offsets (elems): Wx i/o/u, Wh i/o/u, Wfx, Wfh
    const int po = (p < 3) ? p * 65536
                 : (p < 6) ? 196608 + (p - 3) * 65536
                 : (p == 6) ? 393216 : 458752;
    const us8 v = *(const us8*)(wb + po + (size_t)(cg * 32 + col) * 256 + kt * 16 + khs * 8);
    *(us8*)(W + p * 8192 + (kt * 2 + khs) * 256 + col * 8) = v;
  }
  __syncthreads();   // the ONLY barrier — waves free-run after this

  const int lane = tid & 63;
  const int wv   = tid >> 6;           // 0..7
  const int lr   = lane & 31;
  const int kh   = lane >> 5;
  const int colc = cg * 32 + lr;

  // hoisted per-lane biases (colc constant across tiles)
  const float bi_ = bioux[colc];
  const float bo_ = bioux[256 + colc];
  const float bu_ = bioux[512 + colc];
  const float bf_ = LEAF ? 0.f : (bfx[colc] + fb[colc]);

  // per-lane LDS B-frag base: + p*8192 + kt*512 at use
  const unsigned short* LW = W + kh * 256 + lr * 8;

  const int Tper = (T + 31) >> 5;
  const int t0   = stripe * Tper;
  const int tE   = (t0 + Tper < T) ? (t0 + Tper) : T;

  for (int t = t0 + wv; t < tE; t += 8) {
    const int nb0 = t * 32;
    const unsigned short* xrow  = xb + (size_t)(s + nb0 + lr) * 256 + kh * 8;
    const unsigned short* h1row = LEAF ? xrow
        : hb_next + (size_t)(2 * (nb0 + lr)) * 256 + kh * 8;  // h2 = h1row+256

    float cv[16];

    if (!LEAF) {
      // ---- P1: axf = x @ Wfx^T (plane 6) ----
      f32x16 axf = zz16();
      #pragma unroll 4
      for (int kt = 0; kt < 16; ++kt) {
        bf16x8 a = *(const bf16x8*)(xrow + kt * 16);
        bf16x8 b = *(const bf16x8*)(LW + 6 * 8192 + kt * 512);
        axf = MFMA32(a, b, axf);
      }
      f32x16 f1 = axf, f2 = axf;

      // ---- c gathers (issue early; hide under P23) ----
      float c1v[16], c2v[16];
      #pragma unroll
      for (int r = 0; r < 16; ++r) {
        const int m = (r & 3) + 8 * (r >> 2) + 4 * kh;
        const size_t cbo = (size_t)(2 * (nb0 + m)) * 256 + colc;
        c1v[r] = bf2f(cb_next[cbo]);
        c2v[r] = bf2f(cb_next[cbo + 256]);
      }

      // ---- P23: f1 += h1@Wfh, f2 += h2@Wfh (plane 7, B shared) ----
      #pragma unroll 2
      for (int kt = 0; kt < 16; ++kt) {
        bf16x8 b  = *(const bf16x8*)(LW + 7 * 8192 + kt * 512);
        bf16x8 a1 = *(const bf16x8*)(h1row + kt * 16);
        bf16x8 a2 = *(const bf16x8*)(h1row + 256 + kt * 16);
        f1 = MFMA32(a1, b, f1);
        f2 = MFMA32(a2, b, f2);
      }
      #pragma unroll
      for (int r = 0; r < 16; ++r)
        cv[r] = sigm(f1[r] + bf_) * c1v[r] + sigm(f2[r] + bf_) * c2v[r];

      // ---- P4: i,u together (A shared across planes) ----
      f32x16 ai = zz16(), au = zz16();
      #pragma unroll 2
      for (int kt = 0; kt < 16; ++kt) {
        bf16x8 ax = *(const bf16x8*)(xrow + kt * 16);
        bf16x8 a1 = *(const bf16x8*)(h1row + kt * 16);
        bf16x8 a2 = *(const bf16x8*)(h1row + 256 + kt * 16);
        bf16x8 bxi = *(const bf16x8*)(LW + 0 * 8192 + kt * 512);
        bf16x8 bxu = *(const bf16x8*)(LW + 2 * 8192 + kt * 512);
        bf16x8 bhi = *(const bf16x8*)(LW + 3 * 8192 + kt * 512);
        bf16x8 bhu = *(const bf16x8*)(LW + 5 * 8192 + kt * 512);
        ai = MFMA32(ax, bxi, ai);
        ai = MFMA32(a1, bhi, ai);
        ai = MFMA32(a2, bhi, ai);
        au = MFMA32(ax, bxu, au);
        au = MFMA32(a1, bhu, au);
        au = MFMA32(a2, bhu, au);
      }
      #pragma unroll
      for (int r = 0; r < 16; ++r)
        cv[r] += sigm(ai[r] + bi_) * tanh_f(au[r] + bu_);

      // ---- P5: o ----
      f32x16 ao = zz16();
      #pragma unroll 2
      for (int kt = 0; kt < 16; ++kt) {
        bf16x8 ax = *(const bf16x8*)(xrow + kt * 16);
        bf16x8 a1 = *(const bf16x8*)(h1row + kt * 16);
        bf16x8 a2 = *(const bf16x8*)(h1row + 256 + kt * 16);
        bf16x8 bxo = *(const bf16x8*)(LW + 1 * 8192 + kt * 512);
        bf16x8 bho = *(const bf16x8*)(LW + 4 * 8192 + kt * 512);
        ao = MFMA32(ax, bxo, ao);
        ao = MFMA32(a1, bho, ao);
        ao = MFMA32(a2, bho, ao);
      }

      // ---- epilogue ----
      #pragma unroll
      for (int r = 0; r < 16; ++r) {
        const int m = (r & 3) + 8 * (r >> 2) + 4 * kh;
        const int j = nb0 + m;
        if (j >= L) continue;
        const size_t n = (size_t)(s + j);
        const float c_ = cv[r];
        const float hv = sigm(ao[r] + bo_) * tanh_f(c_);
        __builtin_nontemporal_store(hv, h_all + n * 256 + colc);
        cb_cur[(size_t)j * 256 + colc] = f2b(c_);
        hb_cur[(size_t)j * 256 + colc] = f2b(hv);
        if (root && j == 0) { out0[colc] = hv; out0[256 + colc] = c_; }
      }
    } else {
      // ---- leaf: i,u together then o (x only) ----
      f32x16 ai = zz16(), au = zz16();
      #pragma unroll 4
      for (int kt = 0; kt < 16; ++kt) {
        bf16x8 ax  = *(const bf16x8*)(xrow + kt * 16);
        bf16x8 bxi = *(const bf16x8*)(LW + 0 * 8192 + kt * 512);
        bf16x8 bxu = *(const bf16x8*)(LW + 2 * 8192 + kt * 512);
        ai = MFMA32(ax, bxi, ai);
        au = MFMA32(ax, bxu, au);
      }
      #pragma unroll
      for (int r = 0; r < 16; ++r)
        cv[r] = sigm(ai[r] + bi_) * tanh_f(au[r] + bu_);

      f32x16 ao = zz16();
      #pragma unroll 4
      for (int kt = 0; kt < 16; ++kt) {
        bf16x8 ax  = *(const bf16x8*)(xrow + kt * 16);
        bf16x8 bxo = *(const bf16x8*)(LW + 1 * 8192 + kt * 512);
        ao = MFMA32(ax, bxo, ao);
      }

      #pragma unroll
      for (int r = 0; r < 16; ++r) {
        const int m = (r & 3) + 8 * (r >> 2) + 4 * kh;
        const int j = nb0 + m;
        if (j >= L) continue;
        const size_t n = (size_t)(s + j);
        const float c_ = cv[r];
        const float hv = sigm(ao[r] + bo_) * tanh_f(c_);
        __builtin_nontemporal_store(hv, h_all + n * 256 + colc);
        cb_cur[(size_t)j * 256 + colc] = f2b(c_);
        hb_cur[(size_t)j * 256 + colc] = f2b(hv);
      }
    }
  }
}

extern "C" void kernel_launch(void* const* d_in, const int* in_sizes, int n_in,
                              void* d_out, int out_size, void* d_ws, size_t ws_size,
                              hipStream_t stream) {
  const float* inputs = (const float*)d_in[0];
  const float* Wioux  = (const float*)d_in[1];
  const float* bioux  = (const float*)d_in[2];
  const float* Wiouh  = (const float*)d_in[3];
  const float* Wfx    = (const float*)d_in[4];
  const float* bfx    = (const float*)d_in[5];
  const float* Wfh    = (const float*)d_in[6];
  const float* fb     = (const float*)d_in[7];

  const int N = in_sizes[0] / 256;       // 262143
  int depth = 0;
  while (((1 << depth) - 1) < N) ++depth;  // 18
  const int LF = (N + 1) / 2;            // 131072 leaves

  float* out   = (float*)d_out;
  float* h_all = out + 512;

  static bool attr_done = false;
  if (!attr_done) {
    hipFuncSetAttribute((const void*)level_k<0>,
                        hipFuncAttributeMaxDynamicSharedMemorySize, 8 * 16384);
    hipFuncSetAttribute((const void*)level_k<1>,
                        hipFuncAttributeMaxDynamicSharedMemorySize, 3 * 16384);
    attr_done = true;
  }

  // ws carve (bytes): cb ping-pong bf16, hb ping-pong bf16, xb (all) bf16, wb
  char* p = (char*)d_ws;
  unsigned short* cb_even = (unsigned short*)p; p += (size_t)(LF / 2) * 256 * 2;
  unsigned short* cb_odd  = (unsigned short*)p; p += (size_t)LF * 256 * 2;
  unsigned short* hb_even = (unsigned short*)p; p += (size_t)(LF / 2) * 256 * 2;
  unsigned short* hb_odd  = (unsigned short*)p; p += (size_t)LF * 256 * 2;
  unsigned short* xb      = (unsigned short*)p; p += (size_t)N * 256 * 2;
  unsigned short* wb      = (unsigned short*)p;

  pack_w<<<2048, 256, 0, stream>>>(Wioux, Wiouh, Wfx, Wfh, wb);
  {
    const int n8 = (N * 256) / 8;
    conv_x<<<(n8 + 255) / 256, 256, 0, stream>>>(inputs, xb, n8);
  }

  for (int d = depth - 1; d >= 0; --d) {
    const int L = 1 << d;
    const int s = L - 1;
    const int T = (L + 31) / 32;
    unsigned short* cb_cur = (d & 1) ? cb_odd : cb_even;
    const unsigned short* cb_next = ((d + 1) & 1) ? cb_odd : cb_even;
    unsigned short* hb_cur = (d & 1) ? hb_odd : hb_even;
    const unsigned short* hb_next = ((d + 1) & 1) ? hb_odd : hb_even;
    if (d == depth - 1) {
      level_k<1><<<256, 512, 3 * 16384, stream>>>(
          xb, wb, bioux, bfx, fb,
          h_all, cb_cur, cb_next, hb_cur, hb_next, out, s, L, T, 0);
    } else {
      level_k<0><<<256, 512, 8 * 16384, stream>>>(
          xb, wb, bioux, bfx, fb,
          h_all, cb_cur, cb_next, hb_cur, hb_next, out, s, L, T, (d == 0) ? 1 : 0);
    }
  }
}